// Round 2
// baseline (277.231 us; speedup 1.0000x reference)
//
#include <hip/hip_runtime.h>
#include <hip/hip_bf16.h>
#include <math.h>

// ---------------------------------------------------------------------------
// Kernel 1: exclusive prefix sum of sizes[B] -> offs[B]
// Single block, 1024 threads, each thread owns a contiguous chunk of 64.
// ---------------------------------------------------------------------------
__global__ __launch_bounds__(1024) void scan_sizes_kernel(
    const int* __restrict__ sizes, int* __restrict__ offs, int B) {
  __shared__ int part[1024];
  const int t = threadIdx.x;
  const int per = (B + 1023) / 1024;   // 64 for B=65536
  const int start = t * per;
  const int end = min(start + per, B);

  // vectorized partial sum when the chunk is 4-aligned (it is for B=65536)
  int s = 0;
  int i = start;
  if (((start & 3) == 0) && ((end - start) & 3) == 0) {
    const int4* p = reinterpret_cast<const int4*>(sizes + start);
    const int nv = (end - start) >> 2;
    for (int k = 0; k < nv; ++k) {
      int4 v = p[k];
      s += v.x + v.y + v.z + v.w;
    }
    i = end;
  }
  for (; i < end; ++i) s += sizes[i];
  part[t] = s;
  __syncthreads();

  // Hillis-Steele inclusive scan over the 1024 partials
  for (int d = 1; d < 1024; d <<= 1) {
    int v = (t >= d) ? part[t - d] : 0;
    __syncthreads();
    part[t] += v;
    __syncthreads();
  }

  int excl = (t == 0) ? 0 : part[t - 1];
  for (int j = start; j < end; ++j) {
    offs[j] = excl;
    excl += sizes[j];
  }
}

// ---------------------------------------------------------------------------
// Kernel 2: one wave (64 lanes) per segment, 4 waves/block.
// Fast path (n multiple of 4, n <= 512, 16B-aligned offset): segment held in
// registers as 2x float4 per lane -> single global read, single global write.
// Each block of 4 consecutive segments covers one full size cycle
// {128,256,384,512} = 1280 floats -> identical work per block.
// ---------------------------------------------------------------------------
__device__ __forceinline__ float wave_reduce_max(float m) {
#pragma unroll
  for (int d = 32; d >= 1; d >>= 1) m = fmaxf(m, __shfl_xor(m, d, 64));
  return m;
}

__device__ __forceinline__ float wave_reduce_sum(float s) {
#pragma unroll
  for (int d = 32; d >= 1; d >>= 1) s += __shfl_xor(s, d, 64);
  return s;
}

__global__ __launch_bounds__(256) void seg_softmax_kernel(
    const float* __restrict__ x, const int* __restrict__ sizes,
    const int* __restrict__ offs, float* __restrict__ out, int B) {
  const int g = blockIdx.x * 4 + (threadIdx.x >> 6);
  if (g >= B) return;
  const int lane = threadIdx.x & 63;

  const int off = offs[g];
  const int n = sizes[g];

  if (((n & 3) == 0) && ((off & 3) == 0) && n <= 512) {
    // ---- fast path: whole segment in registers ----
    const float4* xp = reinterpret_cast<const float4*>(x + off);
    const bool a0 = (lane * 4) < n;          // chunk 0: elems [0,256)
    const bool a1 = (256 + lane * 4) < n;    // chunk 1: elems [256,512)

    float4 v0 = make_float4(0.f, 0.f, 0.f, 0.f);
    float4 v1 = make_float4(0.f, 0.f, 0.f, 0.f);
    if (a0) v0 = xp[lane];
    if (a1) v1 = xp[64 + lane];

    float m = -INFINITY;
    if (a0) m = fmaxf(fmaxf(v0.x, v0.y), fmaxf(v0.z, v0.w));
    if (a1) m = fmaxf(m, fmaxf(fmaxf(v1.x, v1.y), fmaxf(v1.z, v1.w)));
    m = wave_reduce_max(m);

    float4 e0 = make_float4(0.f, 0.f, 0.f, 0.f);
    float4 e1 = make_float4(0.f, 0.f, 0.f, 0.f);
    float s = 0.f;
    if (a0) {
      e0.x = __expf(v0.x - m);
      e0.y = __expf(v0.y - m);
      e0.z = __expf(v0.z - m);
      e0.w = __expf(v0.w - m);
      s += e0.x + e0.y + e0.z + e0.w;
    }
    if (a1) {
      e1.x = __expf(v1.x - m);
      e1.y = __expf(v1.y - m);
      e1.z = __expf(v1.z - m);
      e1.w = __expf(v1.w - m);
      s += e1.x + e1.y + e1.z + e1.w;
    }
    s = wave_reduce_sum(s);

    const float scale = (float)n / s;
    float4* op = reinterpret_cast<float4*>(out + off);
    if (a0) {
      e0.x *= scale; e0.y *= scale; e0.z *= scale; e0.w *= scale;
      op[lane] = e0;
    }
    if (a1) {
      e1.x *= scale; e1.y *= scale; e1.z *= scale; e1.w *= scale;
      op[64 + lane] = e1;
    }
  } else {
    // ---- generic fallback (any size/alignment); re-reads hit L1/L2 ----
    float m = -INFINITY;
    for (int i = lane; i < n; i += 64) m = fmaxf(m, x[off + i]);
    m = wave_reduce_max(m);

    float s = 0.f;
    for (int i = lane; i < n; i += 64) s += __expf(x[off + i] - m);
    s = wave_reduce_sum(s);

    const float scale = (float)n / s;
    for (int i = lane; i < n; i += 64)
      out[off + i] = __expf(x[off + i] - m) * scale;
  }
}

// ---------------------------------------------------------------------------
extern "C" void kernel_launch(void* const* d_in, const int* in_sizes, int n_in,
                              void* d_out, int out_size, void* d_ws, size_t ws_size,
                              hipStream_t stream) {
  const float* x = (const float*)d_in[0];
  const int* sizes = (const int*)d_in[1];
  // d_in[2] (segment_ids) intentionally unused: offsets derive from sizes.
  float* out = (float*)d_out;
  const int B = in_sizes[1];

  int* offs = (int*)d_ws;  // B ints = 256 KiB of scratch

  scan_sizes_kernel<<<1, 1024, 0, stream>>>(sizes, offs, B);

  const int waves_per_block = 4;
  const int grid = (B + waves_per_block - 1) / waves_per_block;
  seg_softmax_kernel<<<grid, 256, 0, stream>>>(x, sizes, offs, out, B);
}

// Round 3
// 191.053 us; speedup vs baseline: 1.4511x; 1.4511x over previous
//
#include <hip/hip_runtime.h>
#include <hip/hip_bf16.h>
#include <math.h>

#define CHUNK 256  // sizes per block in the scan pipeline

// ---------------------------------------------------------------------------
// Scan stage A: per-block partial sums of sizes. grid = ceil(B/CHUNK).
// ---------------------------------------------------------------------------
__global__ __launch_bounds__(CHUNK) void seg_partial_kernel(
    const int* __restrict__ sizes, int* __restrict__ part, int B) {
  const int b = blockIdx.x, t = threadIdx.x;
  const int i = b * CHUNK + t;
  int v = (i < B) ? sizes[i] : 0;
#pragma unroll
  for (int d = 32; d >= 1; d >>= 1) v += __shfl_xor(v, d, 64);
  __shared__ int red[CHUNK / 64];
  if ((t & 63) == 0) red[t >> 6] = v;
  __syncthreads();
  if (t == 0) {
    int s = 0;
#pragma unroll
    for (int w = 0; w < CHUNK / 64; ++w) s += red[w];
    part[b] = s;
  }
}

// ---------------------------------------------------------------------------
// Scan stage B: single block, exclusive scan of nb partials (nb <= 1024).
// ---------------------------------------------------------------------------
__global__ __launch_bounds__(1024) void scan_part_kernel(
    const int* __restrict__ part, int* __restrict__ base, int nb) {
  __shared__ int sh[1024];
  const int t = threadIdx.x;
  const int v = (t < nb) ? part[t] : 0;
  sh[t] = v;
  __syncthreads();
  for (int d = 1; d < 1024; d <<= 1) {
    int u = (t >= d) ? sh[t - d] : 0;
    __syncthreads();
    sh[t] += u;
    __syncthreads();
  }
  if (t < nb) base[t] = sh[t] - v;  // exclusive
}

// ---------------------------------------------------------------------------
// Scan stage C: per-block exclusive scan + base -> offs. grid = ceil(B/CHUNK).
// ---------------------------------------------------------------------------
__global__ __launch_bounds__(CHUNK) void offs_kernel(
    const int* __restrict__ sizes, const int* __restrict__ base,
    int* __restrict__ offs, int B) {
  const int b = blockIdx.x, t = threadIdx.x;
  const int i = b * CHUNK + t;
  const int v = (i < B) ? sizes[i] : 0;
  __shared__ int sh[CHUNK];
  sh[t] = v;
  __syncthreads();
  for (int d = 1; d < CHUNK; d <<= 1) {
    int u = (t >= d) ? sh[t - d] : 0;
    __syncthreads();
    sh[t] += u;
    __syncthreads();
  }
  if (i < B) offs[i] = base[b] + sh[t] - v;
}

// ---------------------------------------------------------------------------
// Main kernel: one wave (64 lanes) per segment, 4 waves/block.
// Fast path (n mult of 4, n <= 512, 16B-aligned offset): segment held in
// registers as 2x float4 per lane -> single global read, single global write.
// ---------------------------------------------------------------------------
__device__ __forceinline__ float wave_reduce_max(float m) {
#pragma unroll
  for (int d = 32; d >= 1; d >>= 1) m = fmaxf(m, __shfl_xor(m, d, 64));
  return m;
}

__device__ __forceinline__ float wave_reduce_sum(float s) {
#pragma unroll
  for (int d = 32; d >= 1; d >>= 1) s += __shfl_xor(s, d, 64);
  return s;
}

__global__ __launch_bounds__(256) void seg_softmax_kernel(
    const float* __restrict__ x, const int* __restrict__ sizes,
    const int* __restrict__ offs, float* __restrict__ out, int B) {
  const int g = blockIdx.x * 4 + (threadIdx.x >> 6);
  if (g >= B) return;
  const int lane = threadIdx.x & 63;

  const int off = offs[g];
  const int n = sizes[g];

  if (((n & 3) == 0) && ((off & 3) == 0) && n <= 512) {
    // ---- fast path: whole segment in registers ----
    const float4* xp = reinterpret_cast<const float4*>(x + off);
    const bool a0 = (lane * 4) < n;          // chunk 0: elems [0,256)
    const bool a1 = (256 + lane * 4) < n;    // chunk 1: elems [256,512)

    float4 v0 = make_float4(0.f, 0.f, 0.f, 0.f);
    float4 v1 = make_float4(0.f, 0.f, 0.f, 0.f);
    if (a0) v0 = xp[lane];
    if (a1) v1 = xp[64 + lane];

    float m = -INFINITY;
    if (a0) m = fmaxf(fmaxf(v0.x, v0.y), fmaxf(v0.z, v0.w));
    if (a1) m = fmaxf(m, fmaxf(fmaxf(v1.x, v1.y), fmaxf(v1.z, v1.w)));
    m = wave_reduce_max(m);

    float4 e0 = make_float4(0.f, 0.f, 0.f, 0.f);
    float4 e1 = make_float4(0.f, 0.f, 0.f, 0.f);
    float s = 0.f;
    if (a0) {
      e0.x = __expf(v0.x - m);
      e0.y = __expf(v0.y - m);
      e0.z = __expf(v0.z - m);
      e0.w = __expf(v0.w - m);
      s += e0.x + e0.y + e0.z + e0.w;
    }
    if (a1) {
      e1.x = __expf(v1.x - m);
      e1.y = __expf(v1.y - m);
      e1.z = __expf(v1.z - m);
      e1.w = __expf(v1.w - m);
      s += e1.x + e1.y + e1.z + e1.w;
    }
    s = wave_reduce_sum(s);

    const float scale = (float)n / s;
    float4* op = reinterpret_cast<float4*>(out + off);
    if (a0) {
      e0.x *= scale; e0.y *= scale; e0.z *= scale; e0.w *= scale;
      op[lane] = e0;
    }
    if (a1) {
      e1.x *= scale; e1.y *= scale; e1.z *= scale; e1.w *= scale;
      op[64 + lane] = e1;
    }
  } else {
    // ---- generic fallback (any size/alignment); re-reads hit L1/L2 ----
    float m = -INFINITY;
    for (int i = lane; i < n; i += 64) m = fmaxf(m, x[off + i]);
    m = wave_reduce_max(m);

    float s = 0.f;
    for (int i = lane; i < n; i += 64) s += __expf(x[off + i] - m);
    s = wave_reduce_sum(s);

    const float scale = (float)n / s;
    for (int i = lane; i < n; i += 64)
      out[off + i] = __expf(x[off + i] - m) * scale;
  }
}

// ---------------------------------------------------------------------------
extern "C" void kernel_launch(void* const* d_in, const int* in_sizes, int n_in,
                              void* d_out, int out_size, void* d_ws, size_t ws_size,
                              hipStream_t stream) {
  const float* x = (const float*)d_in[0];
  const int* sizes = (const int*)d_in[1];
  // d_in[2] (segment_ids) intentionally unused: offsets derive from sizes.
  float* out = (float*)d_out;
  const int B = in_sizes[1];

  const int nb = (B + CHUNK - 1) / CHUNK;  // 256 for B=65536
  int* offs = (int*)d_ws;                  // [B]
  int* part = offs + B;                    // [nb]
  int* base = part + nb;                   // [nb]

  seg_partial_kernel<<<nb, CHUNK, 0, stream>>>(sizes, part, B);
  scan_part_kernel<<<1, 1024, 0, stream>>>(part, base, nb);
  offs_kernel<<<nb, CHUNK, 0, stream>>>(sizes, base, offs, B);

  const int waves_per_block = 4;
  const int grid = (B + waves_per_block - 1) / waves_per_block;
  seg_softmax_kernel<<<grid, 256, 0, stream>>>(x, sizes, offs, out, B);
}

// Round 4
// 189.821 us; speedup vs baseline: 1.4605x; 1.0065x over previous
//
#include <hip/hip_runtime.h>
#include <hip/hip_bf16.h>
#include <math.h>

// Scan design: chunk = 64 segments.
//   Stage A: part[c] = sum(sizes[64c .. 64c+64))          (256 blocks x 256 thr)
//   Stage B: base[c] = exclusive_prefix(part)[c]          (1 block, 1 wave)
//   Main kernel: offs(g) = base[g>>6] + sum(sizes[(g&~63) .. g))  (in-kernel)

// ---------------------------------------------------------------------------
// Stage A: one wave per chunk of 64 sizes, 4 chunks per block.
// ---------------------------------------------------------------------------
__global__ __launch_bounds__(256) void seg_partial_kernel(
    const int* __restrict__ sizes, int* __restrict__ part, int B, int nb) {
  const int c = blockIdx.x * 4 + (threadIdx.x >> 6);
  if (c >= nb) return;
  const int lane = threadIdx.x & 63;
  const int i = (c << 6) + lane;
  int v = (i < B) ? sizes[i] : 0;
#pragma unroll
  for (int d = 32; d >= 1; d >>= 1) v += __shfl_xor(v, d, 64);
  if (lane == 0) part[c] = v;
}

// ---------------------------------------------------------------------------
// Stage B: single wave exclusive-scans nb (<=1024) partials, 16 per lane.
// No LDS, no barriers: local prefix + shfl_up inclusive scan across lanes.
// ---------------------------------------------------------------------------
__global__ __launch_bounds__(64) void scan_part_kernel(
    const int* __restrict__ part, int* __restrict__ base, int nb) {
  const int lane = threadIdx.x & 63;
  int pre[16];
  int s = 0;
#pragma unroll
  for (int i = 0; i < 16; ++i) {
    const int idx = lane * 16 + i;
    const int t = (idx < nb) ? part[idx] : 0;
    pre[i] = s;          // prefix within this lane's 16 values
    s += t;
  }
  // inclusive scan of s across 64 lanes
  int incl = s;
#pragma unroll
  for (int d = 1; d < 64; d <<= 1) {
    const int u = __shfl_up(incl, d, 64);
    if (lane >= d) incl += u;
  }
  const int excl = incl - s;
#pragma unroll
  for (int i = 0; i < 16; ++i) {
    const int idx = lane * 16 + i;
    if (idx < nb) base[idx] = excl + pre[i];
  }
}

// ---------------------------------------------------------------------------
// Main kernel: one wave per segment, 8 waves per block.
// Offset computed in-kernel: base[chunk] + intra-chunk size sum.
// Fast path (n mult of 4, 16B-aligned offset, n<=512): registers only,
// branchless clamped loads (dup values are no-ops for max, masked for sum).
// ---------------------------------------------------------------------------
__device__ __forceinline__ float wave_reduce_max(float m) {
#pragma unroll
  for (int d = 32; d >= 1; d >>= 1) m = fmaxf(m, __shfl_xor(m, d, 64));
  return m;
}

__device__ __forceinline__ float wave_reduce_sum(float s) {
#pragma unroll
  for (int d = 32; d >= 1; d >>= 1) s += __shfl_xor(s, d, 64);
  return s;
}

__device__ __forceinline__ int wave_reduce_sum_int(int s) {
#pragma unroll
  for (int d = 32; d >= 1; d >>= 1) s += __shfl_xor(s, d, 64);
  return s;
}

__global__ __launch_bounds__(512) void seg_softmax_kernel(
    const float* __restrict__ x, const int* __restrict__ sizes,
    const int* __restrict__ base, float* __restrict__ out, int B) {
  const int g = blockIdx.x * 8 + (threadIdx.x >> 6);
  if (g >= B) return;
  const int lane = threadIdx.x & 63;

  // ---- reconstruct this segment's offset ----
  const int c = g >> 6;            // chunk index
  const int k = g & 63;            // position within chunk
  const int cstart = c << 6;
  int iv = (lane < k) ? sizes[cstart + lane] : 0;
  const int intra = wave_reduce_sum_int(iv);
  const int off = base[c] + intra;
  const int n = sizes[g];

  if (((n & 3) == 0) && ((off & 3) == 0) && n <= 512) {
    // ---- fast path: whole segment in registers ----
    const float4* xp = reinterpret_cast<const float4*>(x + off);
    const int n4 = n >> 2;
    const int i0 = lane;
    const int i1 = 64 + lane;
    const bool a0 = i0 < n4;
    const bool a1 = i1 < n4;

    const float4 v0 = xp[a0 ? i0 : (n4 - 1)];
    const float4 v1 = xp[a1 ? i1 : (n4 - 1)];

    // max: clamped duplicates can't change the result
    float m = fmaxf(fmaxf(v0.x, v0.y), fmaxf(v0.z, v0.w));
    m = fmaxf(m, fmaxf(fmaxf(v1.x, v1.y), fmaxf(v1.z, v1.w)));
    m = wave_reduce_max(m);

    float4 e0, e1;
    e0.x = __expf(v0.x - m);
    e0.y = __expf(v0.y - m);
    e0.z = __expf(v0.z - m);
    e0.w = __expf(v0.w - m);
    e1.x = __expf(v1.x - m);
    e1.y = __expf(v1.y - m);
    e1.z = __expf(v1.z - m);
    e1.w = __expf(v1.w - m);

    float s = (a0 ? (e0.x + e0.y + e0.z + e0.w) : 0.f) +
              (a1 ? (e1.x + e1.y + e1.z + e1.w) : 0.f);
    s = wave_reduce_sum(s);

    const float scale = (float)n / s;
    float4* op = reinterpret_cast<float4*>(out + off);
    if (a0) {
      float4 r;
      r.x = e0.x * scale; r.y = e0.y * scale;
      r.z = e0.z * scale; r.w = e0.w * scale;
      op[i0] = r;
    }
    if (a1) {
      float4 r;
      r.x = e1.x * scale; r.y = e1.y * scale;
      r.z = e1.z * scale; r.w = e1.w * scale;
      op[i1] = r;
    }
  } else {
    // ---- generic fallback (any size/alignment) ----
    float m = -INFINITY;
    for (int i = lane; i < n; i += 64) m = fmaxf(m, x[off + i]);
    m = wave_reduce_max(m);

    float s = 0.f;
    for (int i = lane; i < n; i += 64) s += __expf(x[off + i] - m);
    s = wave_reduce_sum(s);

    const float scale = (float)n / s;
    for (int i = lane; i < n; i += 64)
      out[off + i] = __expf(x[off + i] - m) * scale;
  }
}

// ---------------------------------------------------------------------------
extern "C" void kernel_launch(void* const* d_in, const int* in_sizes, int n_in,
                              void* d_out, int out_size, void* d_ws, size_t ws_size,
                              hipStream_t stream) {
  const float* x = (const float*)d_in[0];
  const int* sizes = (const int*)d_in[1];
  // d_in[2] (segment_ids) intentionally unused: offsets derive from sizes.
  float* out = (float*)d_out;
  const int B = in_sizes[1];

  const int nb = (B + 63) / 64;        // chunks of 64 segments (1024 for 64K)
  int* part = (int*)d_ws;              // [nb]
  int* base = part + nb;               // [nb]

  seg_partial_kernel<<<(nb + 3) / 4, 256, 0, stream>>>(sizes, part, B, nb);
  scan_part_kernel<<<1, 64, 0, stream>>>(part, base, nb);

  seg_softmax_kernel<<<(B + 7) / 8, 512, 0, stream>>>(x, sizes, base, out, B);
}